// Round 6
// baseline (90.020 us; speedup 1.0000x reference)
//
#include <hip/hip_runtime.h>
#include <hip/hip_bf16.h>

// Sliding-window causal attention, B=4, S=4096, d=64, window [i-256, i].
// Round 9: MEASUREMENT ROUND. Device code identical to round 8 (best-known
// structure, 67.3-67.8 µs). The ONLY change: kernel_launch enqueues the
// kernel 3x back-to-back (idempotent: same input -> same output; no sync
// calls, graph-capture safe).
// Purpose: dur ≈ fill + 3*(K+gap) vs r8's fill + (K+gap). Delta/2 = true
// per-launch kernel cost K+gap, which five failed structural theories have
// never actually measured (kernel never appears in top-5 counter rows).
// Readout (pre-committed):
//   dur ~112-120 -> K~24 µs real, keep optimizing device code.
//   dur ~73-85   -> K~3-8 µs; 67 µs floor is poison-fill + fixed overhead
//                   outside kernel control -> declare harness floor.
// Layouts (HW-verified per guide §3): A[m=lane&15][k=quad*8+j];
// C/D col=lane&15, row=quad*4+reg.

#define LOG2E 1.4426950408889634f

typedef __attribute__((ext_vector_type(8))) short  frag;    // 8 bf16
typedef __attribute__((ext_vector_type(4))) float  f32x4;   // C/D

static __device__ inline short f2bf(float x) {
    __hip_bfloat16 h = __float2bfloat16(x);   // RTNE
    return __builtin_bit_cast(short, h);
}

// DPP cross-lane within a 16-lane row: xor1, xor2, then half-mirror (==xor4
// once quad-uniform) and mirror (==xor8 once 8-uniform).
#define DPPF(x, ctrl) __builtin_bit_cast(float, \
    __builtin_amdgcn_mov_dpp(__builtin_bit_cast(int, (x)), (ctrl), 0xF, 0xF, true))

static __device__ inline float red16_max(float x) {
    x = fmaxf(x, DPPF(x, 0xB1));   // quad_perm [1,0,3,2]  (xor 1)
    x = fmaxf(x, DPPF(x, 0x4E));   // quad_perm [2,3,0,1]  (xor 2)
    x = fmaxf(x, DPPF(x, 0x141));  // row_half_mirror      (xor 7 ~ xor 4)
    x = fmaxf(x, DPPF(x, 0x140));  // row_mirror           (xor 15 ~ xor 8)
    return x;
}
static __device__ inline float red16_sum(float x) {
    x += DPPF(x, 0xB1);
    x += DPPF(x, 0x4E);
    x += DPPF(x, 0x141);
    x += DPPF(x, 0x140);
    return x;
}

#define LSTR 70   // K/V/Q LDS row stride (bf16): 35 words == 3 (mod 32)
#define PSTR 42   // P tile row stride: 21 words, ~2-way
#define OSTR 65   // merge buffer row stride (fp32); epilogue-only, once

__global__ __launch_bounds__(512, 2) void swa_mfma9(const float* __restrict__ qkv,
                                                    float* __restrict__ out)
{
    __shared__ short Qs[64 * LSTR];
    __shared__ short Ks[64 * LSTR];
    __shared__ short Vt[64 * LSTR];       // Vt[dim][key]
    __shared__ short Pw[8][16 * PSTR];    // per-wave P (16 q x 32 keys)
    __shared__ float Om[4][16 * OSTR];    // group-1 O partials per stripe
    __shared__ float2 mlbuf[4][16];       // group-1 (m,l) per stripe row

    const int b    = blockIdx.y;
    const int q0   = blockIdx.x * 64;
    const int t    = threadIdx.x;
    const int w    = t >> 6;        // 0..7
    const int s    = w & 3;         // query stripe: rows 16s..16s+15
    const int g    = w >> 2;        // key group: tiles {2g, 2g+1}
    const int lane = t & 63;
    const int cl   = lane & 15;
    const int quad = lane >> 4;
    const int ql   = 4 * quad;

    const float4* qkv4 = (const float4*)qkv;   // 48 float4 per (b,seq) row
    const int r_st = t >> 3;        // staging row 0..63
    const int c8   = t & 7;         // staging float4-col (two: c8, c8+8)

    // ---- stage Q (x 1/8 exact) ----
    {
        const size_t base = (size_t)(b * 4096 + q0 + r_st) * 48;
        #pragma unroll
        for (int i = 0; i < 2; ++i) {
            float4 v = qkv4[base + c8 + 8 * i];
            short4 s4 = { f2bf(v.x * 0.125f), f2bf(v.y * 0.125f),
                          f2bf(v.z * 0.125f), f2bf(v.w * 0.125f) };
            *(short4*)&Qs[r_st * LSTR + 4 * (c8 + 8 * i)] = s4;
        }
    }

    const int c0 = (q0 >= 256) ? 0 : (4 - (q0 >> 6));

    // ---- prefetch chunk c0 ----
    float4 preK[2], preV[2];
    {
        const int kb = q0 - 256 + 64 * c0;
        const size_t base = (size_t)(b * 4096 + kb + r_st) * 48;
        #pragma unroll
        for (int i = 0; i < 2; ++i) {
            preK[i] = qkv4[base + 16 + c8 + 8 * i];
            preV[i] = qkv4[base + 32 + c8 + 8 * i];
        }
    }

    __syncthreads();   // Qs visible
    const frag qf0 = *(const frag*)&Qs[(16 * s + cl) * LSTR + 8 * quad];
    const frag qf1 = *(const frag*)&Qs[(16 * s + cl) * LSTR + 32 + 8 * quad];

    float m[4], l[4];
    f32x4 oacc[4];
    #pragma unroll
    for (int r = 0; r < 4; ++r) { m[r] = -1e30f; l[r] = 0.f; }
    #pragma unroll
    for (int n4 = 0; n4 < 4; ++n4) oacc[n4] = (f32x4){0.f, 0.f, 0.f, 0.f};

    for (int c = c0; c < 5; ++c) {
        __syncthreads();   // A: prev chunk's readers done

        // ---- cvt + store K (row-major) and V (transposed) ----
        #pragma unroll
        for (int i = 0; i < 2; ++i) {
            short4 k4 = { f2bf(preK[i].x), f2bf(preK[i].y),
                          f2bf(preK[i].z), f2bf(preK[i].w) };
            *(short4*)&Ks[r_st * LSTR + 4 * (c8 + 8 * i)] = k4;
            const int d0 = 4 * (c8 + 8 * i);
            Vt[(d0 + 0) * LSTR + r_st] = f2bf(preV[i].x);
            Vt[(d0 + 1) * LSTR + r_st] = f2bf(preV[i].y);
            Vt[(d0 + 2) * LSTR + r_st] = f2bf(preV[i].z);
            Vt[(d0 + 3) * LSTR + r_st] = f2bf(preV[i].w);
        }
        __syncthreads();   // B: tiles visible

        // ---- prefetch next chunk (lands during compute) ----
        if (c < 4) {
            const int kb = q0 - 256 + 64 * (c + 1);
            const size_t base = (size_t)(b * 4096 + kb + r_st) * 48;
            #pragma unroll
            for (int i = 0; i < 2; ++i) {
                preK[i] = qkv4[base + 16 + c8 + 8 * i];
                preV[i] = qkv4[base + 32 + c8 + 8 * i];
            }
        }

        // ---- S = Q K^T over this group's 2 key-tiles ----
        f32x4 sc[2];
        #pragma unroll
        for (int u = 0; u < 2; ++u) {
            const int t4 = 2 * g + u;
            sc[u] = (f32x4){0.f, 0.f, 0.f, 0.f};
            const frag kf0 = *(const frag*)&Ks[(16 * t4 + cl) * LSTR + 8 * quad];
            const frag kf1 = *(const frag*)&Ks[(16 * t4 + cl) * LSTR + 32 + 8 * quad];
            sc[u] = __builtin_amdgcn_mfma_f32_16x16x32_bf16(qf0, kf0, sc[u], 0, 0, 0);
            sc[u] = __builtin_amdgcn_mfma_f32_16x16x32_bf16(qf1, kf1, sc[u], 0, 0, 0);
        }

        // ---- sliding-window mask (edge chunks only) ----
        if (c == 4) {           // causal: keep key <= query
            #pragma unroll
            for (int u = 0; u < 2; ++u) {
                const int t4 = 2 * g + u;
                #pragma unroll
                for (int r = 0; r < 4; ++r)
                    if (16 * s + ql + r < 16 * t4 + cl) sc[u][r] = -1e30f;
            }
        } else if (c == 0) {    // left edge: keep key >= query
            #pragma unroll
            for (int u = 0; u < 2; ++u) {
                const int t4 = 2 * g + u;
                #pragma unroll
                for (int r = 0; r < 4; ++r)
                    if (16 * s + ql + r > 16 * t4 + cl) sc[u][r] = -1e30f;
            }
        }

        // ---- online softmax (DPP 16-lane reductions) ----
        #pragma unroll
        for (int r = 0; r < 4; ++r) {
            float mx = red16_max(fmaxf(sc[0][r], sc[1][r]));
            const float mnew  = fmaxf(m[r], mx);
            const float alpha = __builtin_amdgcn_exp2f((m[r] - mnew) * LOG2E);
            m[r] = mnew;
            float sum = 0.f;
            #pragma unroll
            for (int u = 0; u < 2; ++u) {
                // guard: fully-masked tile would give exp(-1e30 - -1e30)=1
                float p = (sc[u][r] <= -1e29f)
                            ? 0.f
                            : __builtin_amdgcn_exp2f((sc[u][r] - mnew) * LOG2E);
                Pw[w][(ql + r) * PSTR + 16 * u + cl] = f2bf(p);
                sum += p;
            }
            l[r] = l[r] * alpha + red16_sum(sum);
            #pragma unroll
            for (int n4 = 0; n4 < 4; ++n4) oacc[n4][r] *= alpha;
        }

        // ---- O += P V  (P wave-private: lgkmcnt only, no barrier) ----
        const frag pf = *(const frag*)&Pw[w][cl * PSTR + 8 * quad];
        #pragma unroll
        for (int n4 = 0; n4 < 4; ++n4) {
            const frag vf = *(const frag*)&Vt[(16 * n4 + cl) * LSTR + 32 * g + 8 * quad];
            oacc[n4] = __builtin_amdgcn_mfma_f32_16x16x32_bf16(pf, vf, oacc[n4], 0, 0, 0);
        }
    }

    // ---- merge the two key-groups per stripe ----
    if (g == 1) {
        #pragma unroll
        for (int n4 = 0; n4 < 4; ++n4)
            #pragma unroll
            for (int r = 0; r < 4; ++r)
                Om[s][(ql + r) * OSTR + 16 * n4 + cl] = oacc[n4][r];
        if (cl == 0)
            #pragma unroll
            for (int r = 0; r < 4; ++r)
                mlbuf[s][ql + r] = make_float2(m[r], l[r]);
    }
    __syncthreads();
    if (g == 0) {
        #pragma unroll
        for (int r = 0; r < 4; ++r) {
            const float2 ml1 = mlbuf[s][ql + r];
            const float M  = fmaxf(m[r], ml1.x);
            const float a0 = __builtin_amdgcn_exp2f((m[r]  - M) * LOG2E);
            const float a1 = __builtin_amdgcn_exp2f((ml1.x - M) * LOG2E);
            const float L  = l[r] * a0 + ml1.y * a1;
            const float inv = 1.0f / L;
            const size_t row = (size_t)(b * 4096 + q0 + 16 * s + ql + r) * 64;
            #pragma unroll
            for (int n4 = 0; n4 < 4; ++n4) {
                const float o1 = Om[s][(ql + r) * OSTR + 16 * n4 + cl];
                out[row + 16 * n4 + cl] = (oacc[n4][r] * a0 + o1 * a1) * inv;
            }
        }
    }
}

extern "C" void kernel_launch(void* const* d_in, const int* in_sizes, int n_in,
                              void* d_out, int out_size, void* d_ws, size_t ws_size,
                              hipStream_t stream) {
    const float* qkv = (const float*)d_in[0];
    float* out = (float*)d_out;
    dim3 grid(64, 4);
    dim3 block(512);
    // MEASUREMENT: 3 idempotent back-to-back launches.
    // dur ≈ fill + 3*(K+gap); vs r8's fill + (K+gap) -> Delta/2 = K+gap.
    hipLaunchKernelGGL(swa_mfma9, grid, block, 0, stream, qkv, out);
    hipLaunchKernelGGL(swa_mfma9, grid, block, 0, stream, qkv, out);
    hipLaunchKernelGGL(swa_mfma9, grid, block, 0, stream, qkv, out);
}

// Round 7
// 74.918 us; speedup vs baseline: 1.2016x; 1.2016x over previous
//
#include <hip/hip_runtime.h>
#include <hip/hip_bf16.h>

// Sliding-window causal attention, B=4, S=4096, d=64, window [i-256, i].
// Round 10: DS-throughput attack. Measured (r9 3x-launch probe): kernel cost
// K ~= 11.1 us; fixed harness overhead ~= 56.7 us. DS-instruction arithmetic:
// ~1730 cy/chunk of LDS issue (scalar V/P stores + b128 frag reads) ~= 3.6 us
// of K -- invariant under r4-r8's structural changes (explains 5 nulls).
// Change: Q and K fragments now load DIRECT global->register (lane (cl,quad)
// reads exactly K[16t4+cl][8quad..+7]; values bit-identical to staged path).
// Removes Qs/Ks arrays, K-staging writes, and all kf ds_reads: -512 cy/chunk.
// kf loads issue after barrier A -> latency drains at barrier B, hidden under
// the V-store phase. V, P, softmax, masks, merge: byte-identical to r8.
// Layouts (HW-verified per guide §3): A[m=lane&15][k=quad*8+j];
// C/D col=lane&15, row=quad*4+reg.

#define LOG2E 1.4426950408889634f

typedef __attribute__((ext_vector_type(8))) short  frag;    // 8 bf16
typedef __attribute__((ext_vector_type(4))) float  f32x4;   // C/D

static __device__ inline short f2bf(float x) {
    __hip_bfloat16 h = __float2bfloat16(x);   // RTNE
    return __builtin_bit_cast(short, h);
}

// pack 8 floats (two float4) into a bf16 frag, optional scale
static __device__ inline frag pack8s(float4 u, float4 v, float sc) {
    frag r;
    r[0]=f2bf(u.x*sc); r[1]=f2bf(u.y*sc); r[2]=f2bf(u.z*sc); r[3]=f2bf(u.w*sc);
    r[4]=f2bf(v.x*sc); r[5]=f2bf(v.y*sc); r[6]=f2bf(v.z*sc); r[7]=f2bf(v.w*sc);
    return r;
}
static __device__ inline frag pack8n(float4 u, float4 v) {
    frag r;
    r[0]=f2bf(u.x); r[1]=f2bf(u.y); r[2]=f2bf(u.z); r[3]=f2bf(u.w);
    r[4]=f2bf(v.x); r[5]=f2bf(v.y); r[6]=f2bf(v.z); r[7]=f2bf(v.w);
    return r;
}

// DPP cross-lane within a 16-lane row
#define DPPF(x, ctrl) __builtin_bit_cast(float, \
    __builtin_amdgcn_mov_dpp(__builtin_bit_cast(int, (x)), (ctrl), 0xF, 0xF, true))

static __device__ inline float red16_max(float x) {
    x = fmaxf(x, DPPF(x, 0xB1));   // quad_perm xor 1
    x = fmaxf(x, DPPF(x, 0x4E));   // quad_perm xor 2
    x = fmaxf(x, DPPF(x, 0x141));  // row_half_mirror (~xor 4)
    x = fmaxf(x, DPPF(x, 0x140));  // row_mirror      (~xor 8)
    return x;
}
static __device__ inline float red16_sum(float x) {
    x += DPPF(x, 0xB1);
    x += DPPF(x, 0x4E);
    x += DPPF(x, 0x141);
    x += DPPF(x, 0x140);
    return x;
}

#define LSTR 70   // Vt row stride (bf16)
#define PSTR 42   // P tile row stride
#define OSTR 65   // merge buffer row stride (fp32)

__global__ __launch_bounds__(512, 2) void swa_mfma10(const float* __restrict__ qkv,
                                                     float* __restrict__ out)
{
    __shared__ short Vt[64 * LSTR];       // Vt[dim][key]  (only LDS tile left)
    __shared__ short Pw[8][16 * PSTR];    // per-wave P (16 q x 32 keys)
    __shared__ float Om[4][16 * OSTR];    // group-1 O partials per stripe
    __shared__ float2 mlbuf[4][16];       // group-1 (m,l) per stripe row

    const int b    = blockIdx.y;
    const int q0   = blockIdx.x * 64;
    const int t    = threadIdx.x;
    const int w    = t >> 6;        // 0..7
    const int s    = w & 3;         // query stripe: rows 16s..16s+15
    const int g    = w >> 2;        // key group: tiles {2g, 2g+1}
    const int lane = t & 63;
    const int cl   = lane & 15;
    const int quad = lane >> 4;
    const int ql   = 4 * quad;

    const float4* qkv4 = (const float4*)qkv;   // 48 float4 per (b,seq) row
    const int r_st = t >> 3;        // V staging row 0..63
    const int c8   = t & 7;         // V staging float4-col (two: c8, c8+8)

    const int c0 = (q0 >= 256) ? 0 : (4 - (q0 >> 6));

    // ---- Q direct global -> frag (x 1/8 scale folded in) ----
    frag qf0, qf1;
    {
        const size_t qrow = (size_t)(b * 4096 + q0 + 16 * s + cl) * 48;
        const float4 a0 = qkv4[qrow + 2 * quad];
        const float4 a1 = qkv4[qrow + 2 * quad + 1];
        const float4 b0 = qkv4[qrow + 8 + 2 * quad];
        const float4 b1 = qkv4[qrow + 8 + 2 * quad + 1];
        qf0 = pack8s(a0, a1, 0.125f);
        qf1 = pack8s(b0, b1, 0.125f);
    }

    // ---- prefetch V of chunk c0 ----
    float4 preV[2];
    {
        const int kb = q0 - 256 + 64 * c0;
        const size_t base = (size_t)(b * 4096 + kb + r_st) * 48;
        preV[0] = qkv4[base + 32 + c8];
        preV[1] = qkv4[base + 32 + c8 + 8];
    }

    float m[4], l[4];
    f32x4 oacc[4];
    #pragma unroll
    for (int r = 0; r < 4; ++r) { m[r] = -1e30f; l[r] = 0.f; }
    #pragma unroll
    for (int n4 = 0; n4 < 4; ++n4) oacc[n4] = (f32x4){0.f, 0.f, 0.f, 0.f};

    for (int c = c0; c < 5; ++c) {
        const int kb = q0 - 256 + 64 * c;

        __syncthreads();   // A: prev chunk's Vt readers done

        // ---- K direct loads (in flight during V-store; drained at barrier B)
        float4 kA0[2], kA1[2], kB0[2], kB1[2];
        #pragma unroll
        for (int u = 0; u < 2; ++u) {
            const size_t krow = (size_t)(b * 4096 + kb + 16 * (2 * g + u) + cl) * 48;
            kA0[u] = qkv4[krow + 16 + 2 * quad];
            kA1[u] = qkv4[krow + 16 + 2 * quad + 1];
            kB0[u] = qkv4[krow + 24 + 2 * quad];
            kB1[u] = qkv4[krow + 24 + 2 * quad + 1];
        }

        // ---- cvt + store V (transposed) ----
        #pragma unroll
        for (int i = 0; i < 2; ++i) {
            const int d0 = 4 * (c8 + 8 * i);
            Vt[(d0 + 0) * LSTR + r_st] = f2bf(preV[i].x);
            Vt[(d0 + 1) * LSTR + r_st] = f2bf(preV[i].y);
            Vt[(d0 + 2) * LSTR + r_st] = f2bf(preV[i].z);
            Vt[(d0 + 3) * LSTR + r_st] = f2bf(preV[i].w);
        }
        __syncthreads();   // B: Vt visible (+ kf loads drained)

        // ---- prefetch next chunk's V (lands during compute) ----
        if (c < 4) {
            const size_t base = (size_t)(b * 4096 + kb + 64 + r_st) * 48;
            preV[0] = qkv4[base + 32 + c8];
            preV[1] = qkv4[base + 32 + c8 + 8];
        }

        // ---- S = Q K^T over this group's 2 key-tiles ----
        f32x4 sc[2];
        #pragma unroll
        for (int u = 0; u < 2; ++u) {
            sc[u] = (f32x4){0.f, 0.f, 0.f, 0.f};
            const frag kf0 = pack8n(kA0[u], kA1[u]);
            const frag kf1 = pack8n(kB0[u], kB1[u]);
            sc[u] = __builtin_amdgcn_mfma_f32_16x16x32_bf16(qf0, kf0, sc[u], 0, 0, 0);
            sc[u] = __builtin_amdgcn_mfma_f32_16x16x32_bf16(qf1, kf1, sc[u], 0, 0, 0);
        }

        // ---- sliding-window mask (edge chunks only) ----
        if (c == 4) {           // causal: keep key <= query
            #pragma unroll
            for (int u = 0; u < 2; ++u) {
                const int t4 = 2 * g + u;
                #pragma unroll
                for (int r = 0; r < 4; ++r)
                    if (16 * s + ql + r < 16 * t4 + cl) sc[u][r] = -1e30f;
            }
        } else if (c == 0) {    // left edge: keep key >= query
            #pragma unroll
            for (int u = 0; u < 2; ++u) {
                const int t4 = 2 * g + u;
                #pragma unroll
                for (int r = 0; r < 4; ++r)
                    if (16 * s + ql + r > 16 * t4 + cl) sc[u][r] = -1e30f;
            }
        }

        // ---- online softmax (DPP 16-lane reductions) ----
        #pragma unroll
        for (int r = 0; r < 4; ++r) {
            float mx = red16_max(fmaxf(sc[0][r], sc[1][r]));
            const float mnew  = fmaxf(m[r], mx);
            const float alpha = __builtin_amdgcn_exp2f((m[r] - mnew) * LOG2E);
            m[r] = mnew;
            float sum = 0.f;
            #pragma unroll
            for (int u = 0; u < 2; ++u) {
                // guard: fully-masked tile would give exp(-1e30 - -1e30)=1
                float p = (sc[u][r] <= -1e29f)
                            ? 0.f
                            : __builtin_amdgcn_exp2f((sc[u][r] - mnew) * LOG2E);
                Pw[w][(ql + r) * PSTR + 16 * u + cl] = f2bf(p);
                sum += p;
            }
            l[r] = l[r] * alpha + red16_sum(sum);
            #pragma unroll
            for (int n4 = 0; n4 < 4; ++n4) oacc[n4][r] *= alpha;
        }

        // ---- O += P V  (P wave-private: lgkmcnt only, no barrier) ----
        const frag pf = *(const frag*)&Pw[w][cl * PSTR + 8 * quad];
        #pragma unroll
        for (int n4 = 0; n4 < 4; ++n4) {
            const frag vf = *(const frag*)&Vt[(16 * n4 + cl) * LSTR + 32 * g + 8 * quad];
            oacc[n4] = __builtin_amdgcn_mfma_f32_16x16x32_bf16(pf, vf, oacc[n4], 0, 0, 0);
        }
    }

    // ---- merge the two key-groups per stripe ----
    if (g == 1) {
        #pragma unroll
        for (int n4 = 0; n4 < 4; ++n4)
            #pragma unroll
            for (int r = 0; r < 4; ++r)
                Om[s][(ql + r) * OSTR + 16 * n4 + cl] = oacc[n4][r];
        if (cl == 0)
            #pragma unroll
            for (int r = 0; r < 4; ++r)
                mlbuf[s][ql + r] = make_float2(m[r], l[r]);
    }
    __syncthreads();
    if (g == 0) {
        #pragma unroll
        for (int r = 0; r < 4; ++r) {
            const float2 ml1 = mlbuf[s][ql + r];
            const float M  = fmaxf(m[r], ml1.x);
            const float a0 = __builtin_amdgcn_exp2f((m[r]  - M) * LOG2E);
            const float a1 = __builtin_amdgcn_exp2f((ml1.x - M) * LOG2E);
            const float L  = l[r] * a0 + ml1.y * a1;
            const float inv = 1.0f / L;
            const size_t row = (size_t)(b * 4096 + q0 + 16 * s + ql + r) * 64;
            #pragma unroll
            for (int n4 = 0; n4 < 4; ++n4) {
                const float o1 = Om[s][(ql + r) * OSTR + 16 * n4 + cl];
                out[row + 16 * n4 + cl] = (oacc[n4][r] * a0 + o1 * a1) * inv;
            }
        }
    }
}

extern "C" void kernel_launch(void* const* d_in, const int* in_sizes, int n_in,
                              void* d_out, int out_size, void* d_ws, size_t ws_size,
                              hipStream_t stream) {
    const float* qkv = (const float*)d_in[0];
    float* out = (float*)d_out;
    dim3 grid(64, 4);
    dim3 block(512);
    hipLaunchKernelGGL(swa_mfma10, grid, block, 0, stream, qkv, out);
}

// Round 8
// 67.411 us; speedup vs baseline: 1.3354x; 1.1114x over previous
//
#include <hip/hip_runtime.h>
#include <hip/hip_bf16.h>

// Sliding-window causal attention, B=4, S=4096, d=64, window [i-256, i].
// Round 11: swapped-QK^T in-register-softmax redesign (guide §B structure).
//  - QK computed as mfma(K, Q) -> S^T: lane (cl,quad) holds S[key=16u+4q+r][q=cl]
//    for ONE query (q=16s+cl). Softmax: local 8-max tree + 2 shfl_xor (vs 4x
//    4-deep DPP chains); alpha/m/l are lane-local scalars; exp2 12->9.
//  - P never touches LDS: 2-stage butterfly (4 shfl_xor + selects, verified
//    by hand: quad1.F0 <- quad0.c2 <- quad2.a0 = keys(8,9) etc.) rearranges
//    bf16-packed P into the PV B-fragment. Kills the per-chunk 8x ds_write
//    + lgkmcnt + ds_read_b128 round trip (~250 cy serial, x5 chunks).
//  - PV swapped too: mfma(A=Vt, B=P) -> O[dim=16n4+4q+r][q=cl]; Vt read is
//    byte-identical to r8. Output: 4 packed float4 stores/lane.
//  - K/V/Q staging, barriers, chunk loop: byte-identical to r8 (best-known).
// LDS ~44.8 KB. Layouts (HW-verified per guide §3): A/B[row=lane&15][k=quad*8+j];
// C/D col=lane&15, row=quad*4+reg.

#define LOG2E 1.4426950408889634f

typedef __attribute__((ext_vector_type(8))) short  frag;    // 8 bf16
typedef __attribute__((ext_vector_type(4))) float  f32x4;   // C/D

static __device__ inline short f2bf(float x) {
    __hip_bfloat16 h = __float2bfloat16(x);   // RTNE
    return __builtin_bit_cast(short, h);
}
static __device__ inline unsigned pkbf(float x, float y) {
    return (unsigned)(unsigned short)__builtin_bit_cast(short, __float2bfloat16(x))
         | ((unsigned)(unsigned short)__builtin_bit_cast(short, __float2bfloat16(y)) << 16);
}

#define LSTR 70   // K/V/Q LDS row stride (bf16)
#define OMS  17   // Om per-lane dword stride (17 coprime 32: conflict-free)

__global__ __launch_bounds__(512, 2) void swa_mfma11(const float* __restrict__ qkv,
                                                     float* __restrict__ out)
{
    __shared__ short Qs[64 * LSTR];        // 8960 B
    __shared__ short Ks[64 * LSTR];        // 8960 B
    __shared__ short Vt[64 * LSTR];        // 8960 B  Vt[dim][key]
    __shared__ float Om[4][64 * OMS];      // 17408 B g1 O partials per stripe
    __shared__ float2 mlbuf[4][16];        //   512 B g1 (m,l) per query col

    const int b    = blockIdx.y;
    const int q0   = blockIdx.x * 64;
    const int t    = threadIdx.x;
    const int w    = t >> 6;        // 0..7
    const int s    = w & 3;         // query stripe: rows 16s..16s+15
    const int g    = w >> 2;        // key group: tiles {2g, 2g+1}
    const int lane = t & 63;
    const int cl   = lane & 15;
    const int quad = lane >> 4;
    const int ql   = 4 * quad;
    const int hb   = quad >> 1;     // quad high bit
    const int lb   = quad & 1;      // quad low bit

    const float4* qkv4 = (const float4*)qkv;   // 48 float4 per (b,seq) row
    const int r_st = t >> 3;        // staging row 0..63
    const int c8   = t & 7;         // staging float4-col (two: c8, c8+8)

    // ---- stage Q (x 1/8 exact) ----
    {
        const size_t base = (size_t)(b * 4096 + q0 + r_st) * 48;
        #pragma unroll
        for (int i = 0; i < 2; ++i) {
            float4 v = qkv4[base + c8 + 8 * i];
            short4 s4 = { f2bf(v.x * 0.125f), f2bf(v.y * 0.125f),
                          f2bf(v.z * 0.125f), f2bf(v.w * 0.125f) };
            *(short4*)&Qs[r_st * LSTR + 4 * (c8 + 8 * i)] = s4;
        }
    }

    const int c0 = (q0 >= 256) ? 0 : (4 - (q0 >> 6));

    // ---- prefetch chunk c0 ----
    float4 preK[2], preV[2];
    {
        const int kb = q0 - 256 + 64 * c0;
        const size_t base = (size_t)(b * 4096 + kb + r_st) * 48;
        #pragma unroll
        for (int i = 0; i < 2; ++i) {
            preK[i] = qkv4[base + 16 + c8 + 8 * i];
            preV[i] = qkv4[base + 32 + c8 + 8 * i];
        }
    }

    __syncthreads();   // Qs visible
    // B-operand Q fragment: q-row 16s+cl, dims 8*quad..+7 (+32 for second K-half)
    const frag qf0 = *(const frag*)&Qs[(16 * s + cl) * LSTR + 8 * quad];
    const frag qf1 = *(const frag*)&Qs[(16 * s + cl) * LSTR + 32 + 8 * quad];

    float m = -1e30f, l = 0.f;
    f32x4 oacc[4];
    #pragma unroll
    for (int n4 = 0; n4 < 4; ++n4) oacc[n4] = (f32x4){0.f, 0.f, 0.f, 0.f};

    for (int c = c0; c < 5; ++c) {
        __syncthreads();   // A: prev chunk's readers done

        // ---- cvt + store K (row-major) and V (transposed) ----
        #pragma unroll
        for (int i = 0; i < 2; ++i) {
            short4 k4 = { f2bf(preK[i].x), f2bf(preK[i].y),
                          f2bf(preK[i].z), f2bf(preK[i].w) };
            *(short4*)&Ks[r_st * LSTR + 4 * (c8 + 8 * i)] = k4;
            const int d0 = 4 * (c8 + 8 * i);
            Vt[(d0 + 0) * LSTR + r_st] = f2bf(preV[i].x);
            Vt[(d0 + 1) * LSTR + r_st] = f2bf(preV[i].y);
            Vt[(d0 + 2) * LSTR + r_st] = f2bf(preV[i].z);
            Vt[(d0 + 3) * LSTR + r_st] = f2bf(preV[i].w);
        }
        __syncthreads();   // B: tiles visible

        // ---- prefetch next chunk (lands during compute) ----
        if (c < 4) {
            const int kb = q0 - 256 + 64 * (c + 1);
            const size_t base = (size_t)(b * 4096 + kb + r_st) * 48;
            #pragma unroll
            for (int i = 0; i < 2; ++i) {
                preK[i] = qkv4[base + 16 + c8 + 8 * i];
                preV[i] = qkv4[base + 32 + c8 + 8 * i];
            }
        }

        // ---- S^T = K Q^T over this group's 2 key-tiles (SWAPPED operands) ----
        // sc[u][r] = S[key = 16(2g+u) + ql + r][q = 16s + cl]
        f32x4 sc[2];
        #pragma unroll
        for (int u = 0; u < 2; ++u) {
            const int t4 = 2 * g + u;
            sc[u] = (f32x4){0.f, 0.f, 0.f, 0.f};
            const frag kf0 = *(const frag*)&Ks[(16 * t4 + cl) * LSTR + 8 * quad];
            const frag kf1 = *(const frag*)&Ks[(16 * t4 + cl) * LSTR + 32 + 8 * quad];
            sc[u] = __builtin_amdgcn_mfma_f32_16x16x32_bf16(kf0, qf0, sc[u], 0, 0, 0);
            sc[u] = __builtin_amdgcn_mfma_f32_16x16x32_bf16(kf1, qf1, sc[u], 0, 0, 0);
        }

        // ---- sliding-window mask (edge chunks only; roles of cl and ql+r swap)
        if (c == 4) {           // causal: keep key <= query; key=16t4+ql+r, q=16s+cl
            #pragma unroll
            for (int u = 0; u < 2; ++u) {
                const int t4 = 2 * g + u;
                #pragma unroll
                for (int r = 0; r < 4; ++r)
                    if (16 * t4 + ql + r > 16 * s + cl) sc[u][r] = -1e30f;
            }
        } else if (c == 0) {    // left edge: keep key >= query
            #pragma unroll
            for (int u = 0; u < 2; ++u) {
                const int t4 = 2 * g + u;
                #pragma unroll
                for (int r = 0; r < 4; ++r)
                    if (16 * t4 + ql + r < 16 * s + cl) sc[u][r] = -1e30f;
            }
        }

        // ---- online softmax: one query per lane, cross-quad reduce ----
        float mx = fmaxf(fmaxf(fmaxf(sc[0][0], sc[0][1]), fmaxf(sc[0][2], sc[0][3])),
                         fmaxf(fmaxf(sc[1][0], sc[1][1]), fmaxf(sc[1][2], sc[1][3])));
        mx = fmaxf(mx, __shfl_xor(mx, 16));
        mx = fmaxf(mx, __shfl_xor(mx, 32));
        const float mnew  = fmaxf(m, mx);
        const float alpha = __builtin_amdgcn_exp2f((m - mnew) * LOG2E);
        m = mnew;
        float p[8];
        float sum = 0.f;
        #pragma unroll
        for (int u = 0; u < 2; ++u)
            #pragma unroll
            for (int r = 0; r < 4; ++r) {
                // guard: fully-masked tile would give exp(-1e30 - -1e30)=1
                const float pv = (sc[u][r] <= -1e29f)
                                   ? 0.f
                                   : __builtin_amdgcn_exp2f((sc[u][r] - mnew) * LOG2E);
                p[4 * u + r] = pv;
                sum += pv;
            }
        sum += __shfl_xor(sum, 16);
        sum += __shfl_xor(sum, 32);
        l = l * alpha + sum;
        #pragma unroll
        for (int n4 = 0; n4 < 4; ++n4) oacc[n4] *= alpha;

        // ---- in-register P redistribution (2-stage butterfly) ----
        // a[d=2u+pair]: bf16 pair (keys 16u + ql + 2*pair + {0,1}) of query cl
        const unsigned a0 = pkbf(p[0], p[1]);
        const unsigned a1 = pkbf(p[2], p[3]);
        const unsigned a2 = pkbf(p[4], p[5]);
        const unsigned a3 = pkbf(p[6], p[7]);
        // stage 1 (xor 32): route by u; send the pair the partner keeps
        const unsigned u0s = hb == 0 ? a2 : a0;
        const unsigned u1s = hb == 0 ? a3 : a1;
        const unsigned r0 = __shfl_xor((int)u0s, 32);
        const unsigned r1 = __shfl_xor((int)u1s, 32);
        const unsigned cc0 = hb == 0 ? a0 : r0;   // quad(q1=0,q0=lb), u=hb
        const unsigned cc1 = hb == 0 ? a1 : r1;
        const unsigned cc2 = hb == 0 ? r0 : a2;   // quad(q1=1,q0=lb)
        const unsigned cc3 = hb == 0 ? r1 : a3;
        // stage 2 (xor 16): route by source-q1
        const unsigned v0 = lb == 0 ? cc2 : cc0;
        const unsigned v1 = lb == 0 ? cc3 : cc1;
        const unsigned w0 = __shfl_xor((int)v0, 16);
        const unsigned w1 = __shfl_xor((int)v1, 16);
        unsigned F[4];
        F[0] = lb == 0 ? cc0 : w0;   // keys 8*quad+0,1 (of query cl)
        F[1] = lb == 0 ? cc1 : w1;   // keys 8*quad+2,3
        F[2] = lb == 0 ? w0 : cc2;   // keys 8*quad+4,5
        F[3] = lb == 0 ? w1 : cc3;   // keys 8*quad+6,7
        const frag pfr = __builtin_bit_cast(frag, *(uint4*)F);

        // ---- O^T += V^T P : A=Vt[dim][key] (read identical to r8), B=P ----
        #pragma unroll
        for (int n4 = 0; n4 < 4; ++n4) {
            const frag vf = *(const frag*)&Vt[(16 * n4 + cl) * LSTR + 32 * g + 8 * quad];
            oacc[n4] = __builtin_amdgcn_mfma_f32_16x16x32_bf16(vf, pfr, oacc[n4], 0, 0, 0);
        }
        // oacc[n4][r] = O[dim = 16*n4 + ql + r][q = 16s + cl]
    }

    // ---- merge the two key-groups per stripe (all per-lane scalar) ----
    if (g == 1) {
        #pragma unroll
        for (int n4 = 0; n4 < 4; ++n4)
            #pragma unroll
            for (int r = 0; r < 4; ++r)
                Om[s][lane * OMS + 4 * n4 + r] = oacc[n4][r];
        if (quad == 0) mlbuf[s][cl] = make_float2(m, l);
    }
    __syncthreads();
    if (g == 0) {
        const float2 ml1 = mlbuf[s][cl];
        const float M  = fmaxf(m, ml1.x);
        const float a0 = __builtin_amdgcn_exp2f((m     - M) * LOG2E);
        const float a1 = __builtin_amdgcn_exp2f((ml1.x - M) * LOG2E);
        const float L  = l * a0 + ml1.y * a1;
        const float inv = 1.0f / L;
        const size_t row = (size_t)(b * 4096 + q0 + 16 * s + cl) * 64;
        #pragma unroll
        for (int n4 = 0; n4 < 4; ++n4) {
            float4 o;
            o.x = (oacc[n4][0] * a0 + Om[s][lane * OMS + 4 * n4 + 0] * a1) * inv;
            o.y = (oacc[n4][1] * a0 + Om[s][lane * OMS + 4 * n4 + 1] * a1) * inv;
            o.z = (oacc[n4][2] * a0 + Om[s][lane * OMS + 4 * n4 + 2] * a1) * inv;
            o.w = (oacc[n4][3] * a0 + Om[s][lane * OMS + 4 * n4 + 3] * a1) * inv;
            *(float4*)&out[row + 16 * n4 + ql] = o;
        }
    }
}

extern "C" void kernel_launch(void* const* d_in, const int* in_sizes, int n_in,
                              void* d_out, int out_size, void* d_ws, size_t ws_size,
                              hipStream_t stream) {
    const float* qkv = (const float*)d_in[0];
    float* out = (float*)d_out;
    dim3 grid(64, 4);
    dim3 block(512);
    hipLaunchKernelGGL(swa_mfma11, grid, block, 0, stream, qkv, out);
}